// Round 13
// baseline (38.750 us; speedup 1.0000x reference)
//
#include <hip/hip_runtime.h>

// Maj3: out[b,o,h,w] = sum_{kh,c} sign( sum_{kw} x[b,c,h+kh-1,w+kw-1] * W[o,kw,kh,c] )
// x: (4,64,56,56) f32; W: (64,3,3,64) f32; out: (4,64,56,56) f32.
// Bit-exactness vs numpy required (integer output, threshold 1.36): no FMA
// contraction (contract(off) pragma — verified holding, absmax stable 1.0),
// same per-channel mul/add order, sign(0)=0 only from fully-pad rows (skipped).
//
// R13: R12's VGPR_Count=32 exposed pressure-driven rematerialization — under
// the (256,6) 85-VGPR cap the allocator re-derived DPP taps/addresses per oo
// instead of keeping them live, inflating dynamic VALU ~45% vs R11 (busy 27.6
// vs 18.9us). One change: launch_bounds(256,4) -> 128-VGPR cap. Keeps R12's
// stall-free LDS weight path AND R11's lean instruction stream. 16 waves/CU.

#define Cn 64
#define Hn 56
#define Wn 56
#define On 64
#define OG 8    // output channels per block
#define CH 16   // channels per wave (c-quarter); power of 2 (wrap mask)

#define DPP_WAVE_SHL1 0x130
#define DPP_WAVE_SHR1 0x138

// Whole-wave shift by one lane; out-of-range source lanes read 0 (exact pad).
__device__ __forceinline__ float dpp_shift(float s, const int ctrl_is_shr) {
    const int si = __builtin_bit_cast(int, s);
    const int r  = ctrl_is_shr
        ? __builtin_amdgcn_update_dpp(0, si, DPP_WAVE_SHR1, 0xf, 0xf, true)
        : __builtin_amdgcn_update_dpp(0, si, DPP_WAVE_SHL1, 0xf, 0xf, true);
    return __builtin_bit_cast(float, r);
}

__global__ __launch_bounds__(256, 4)
void maj3_kernel(const float* __restrict__ x,
                 const float* __restrict__ wt,
                 float* __restrict__ out)
{
#pragma clang fp contract(off)
    // 18432 B: weight slice [oo][kw][kh][c] (same layout as wt); the combine
    // buffer aliases the front of it after compute (sync-guarded).
    __shared__ __align__(16) char smem[OG * 9 * Cn * 4];
    float* wlds = (float*)smem;

    const int lane = threadIdx.x & 63;
    // Wave-uniform; readfirstlane keeps derived values on the scalar path.
    const int cq   = __builtin_amdgcn_readfirstlane((int)(threadIdx.x >> 6)); // 0..3
    const int bh   = blockIdx.x;        // 0..223: one (b,h) row per block
    const int b    = bh / Hn;
    const int h    = bh - b * Hn;
    const int og   = blockIdx.y * OG;   // block-uniform o base

    // Stage this block's weight slice into LDS (bit-exact copy, coalesced).
    {
        const float4* src = (const float4*)(wt + og * (9 * Cn));
        float4* dst = (float4*)wlds;
        for (int i = threadIdx.x; i < (OG * 9 * Cn) / 4; i += 256)
            dst[i] = src[i];
    }
    __syncthreads();

    const int wc   = lane;              // pixel column; lanes >=56 inactive
    const bool act = wc < Wn;
    const int c1   = min(wc, Wn - 1);   // clamped own-tap address

#define LDX(cc) (act ? xr[(cc) * (Hn * Wn) + c1] : 0.0f)

    int acc[OG];
    #pragma unroll
    for (int i = 0; i < OG; ++i) acc[i] = 0;

    int nvalid = 0;
    const float* xb = x + b * (Cn * Hn * Wn) + cq * (CH * Hn * Wn);

    for (int kh = 0; kh < 3; ++kh) {
        const int row = h + kh - 1;
        if (row < 0 || row >= Hn) continue;   // fully-pad row: sign(0)=0, skip
        ++nvalid;
        const float* xr = xb + row * Wn;

        // Prologue: tile 0's x values in named regs (one-tile-ahead pipeline).
        float xa0 = LDX(0), xa1 = LDX(1), xa2 = LDX(2), xa3 = LDX(3);

        #pragma clang loop unroll(disable)
        for (int ct = 0; ct < CH; ct += 4) {
            // Prefetch next x tile (wraps on last iter: harmless reload).
            const int cn = (ct + 4) & (CH - 1);
            const float nb0 = LDX(cn + 0);
            const float nb1 = LDX(cn + 1);
            const float nb2 = LDX(cn + 2);
            const float nb3 = LDX(cn + 3);

            // Neighbor taps once per channel, shared across all 8 oo.
            const float xl0 = dpp_shift(xa0, 1), xh0 = dpp_shift(xa0, 0);
            const float xl1 = dpp_shift(xa1, 1), xh1 = dpp_shift(xa1, 0);
            const float xl2 = dpp_shift(xa2, 1), xh2 = dpp_shift(xa2, 0);
            const float xl3 = dpp_shift(xa3, 1), xh3 = dpp_shift(xa3, 0);

            #pragma unroll
            for (int oo = 0; oo < OG; ++oo) {
                // wlds[(oo*9 + kw*3 + kh)*64 + cq*16 + ct .. +3], kw = 0,1,2:
                const int wbase = (oo * 9 + kh) * Cn + cq * CH + ct;
                const float4 w0 = *(const float4*)&wlds[wbase + 0 * 3 * Cn];
                const float4 w1 = *(const float4*)&wlds[wbase + 1 * 3 * Cn];
                const float4 w2 = *(const float4*)&wlds[wbase + 2 * 3 * Cn];
                // Per channel: p0=x[w-1]*W(kw0), p1=x[w]*W(kw1), p2=x[w+1]*W(kw2),
                // s=(p0+p1)+p2 — reference order, contract(off).
                const float s0 = (xl0 * w0.x + xa0 * w1.x) + xh0 * w2.x;
                const float s1 = (xl1 * w0.y + xa1 * w1.y) + xh1 * w2.y;
                const float s2 = (xl2 * w0.z + xa2 * w1.z) + xh2 * w2.z;
                const float s3 = (xl3 * w0.w + xa3 * w1.w) + xh3 * w2.w;
                // Integer negative-count (exact): paired adds -> v_add3.
                acc[oo] += (int)(((__float_as_uint(s0) >> 31) +
                                  (__float_as_uint(s1) >> 31)) +
                                 ((__float_as_uint(s2) >> 31) +
                                  (__float_as_uint(s3) >> 31)));
            }
            xa0 = nb0; xa1 = nb1; xa2 = nb2; xa3 = nb3;
        }
    }

    // Reuse the weight LDS as the combine buffer (all reads are done).
    __syncthreads();
    int (*cbuf)[OG][64] = (int (*)[OG][64])smem;
    if (cq != 0) {
        #pragma unroll
        for (int oo = 0; oo < OG; ++oo) cbuf[cq - 1][oo][lane] = acc[oo];
    }
    __syncthreads();
    if (cq == 0 && act) {
        float* ob = out + ((b * On + og) * Hn + h) * Wn + wc;
        const float base = (float)(nvalid * Cn);
        #pragma unroll
        for (int oo = 0; oo < OG; ++oo) {
            const int total = acc[oo] + cbuf[0][oo][lane]
                            + cbuf[1][oo][lane] + cbuf[2][oo][lane];
            ob[oo * Hn * Wn] = base - 2.0f * (float)total;  // N - 2*negcount
        }
    }
}

extern "C" void kernel_launch(void* const* d_in, const int* in_sizes, int n_in,
                              void* d_out, int out_size, void* d_ws, size_t ws_size,
                              hipStream_t stream) {
    const float* x  = (const float*)d_in[0];
    const float* wt = (const float*)d_in[1];
    float* o        = (float*)d_out;
    dim3 grid(224, 8);   // 224 (b,h) rows x 8 o-groups of 8
    maj3_kernel<<<grid, dim3(256), 0, stream>>>(x, wt, o);
}

// Round 15
// 32.497 us; speedup vs baseline: 1.1924x; 1.1924x over previous
//
#include <hip/hip_runtime.h>

// Maj3: out[b,o,h,w] = sum_{kh,c} sign( sum_{kw} x[b,c,h+kh-1,w+kw-1] * W[o,kw,kh,c] )
// x: (4,64,56,56) f32; W: (64,3,3,64) f32; out: (4,64,56,56) f32.
// Bit-exactness vs numpy required (threshold 1.36, integer output): contract(off),
// reference mul/add order per sign. Padded rows staged as 0.0 -> sums are +-0;
// the (s < 0) predicate counts neither, and base=nvalid*64 excludes them.
//
// R15: R14 design, compile fix only — __builtin_amdgcn_writelane doesn't exist
// on this clang; emit v_writelane_b32 via inline asm (count is wave-uniform ->
// SGPR via readfirstlane; lane index compile-time under full unroll).
//
// Design recap (lane = channel c, the sign-count axis):
//  - W[o,kw,kh,lane]: coalesced per-lane load, wave's 4-o set = 36 VGPRs,
//    loaded ONCE -> zero weight traffic in the main loop (R5-R13's bottleneck).
//  - Signs counted 64/instr: v_cmp (ballot) -> s_bcnt1 -> writelane.
//  - x staged once into LDS [3][64][31] (odd stride -> 2 lanes/bank = free),
//    sliding 3-tap window, 3 ds_read_b32 per pixel.
//  - Per-pixel counts land in lane p -> coalesced lane=w store.

#define Cn 64
#define Hn 56
#define Wn 56
#define On 64
#define OG 4        // output channels per wave
#define PIX 28      // pixels per wave (half row)
#define SLABW 30    // staged taps per row: w0-1 .. w0+28
#define SLABP 31    // padded stride (odd -> bank-conflict-free column reads)

// v_writelane_b32: write wave-uniform `val` into lane `LANE` of `dst`.
// (No clang builtin for writelane on this toolchain — inline asm, non-volatile
// so the scheduler may move it freely; value-tied via "+v".)
#define WRITELANE(dst, val, LANE)                                             \
    asm("v_writelane_b32 %0, %1, " #LANE                                      \
        : "+v"(dst) : "s"(val))

__global__ __launch_bounds__(512, 4)
void maj3_kernel(const float* __restrict__ x,
                 const float* __restrict__ wt,
                 float* __restrict__ out)
{
#pragma clang fp contract(off)
    __shared__ float slab[3][Cn][SLABP];

    const int lane  = threadIdx.x & 63;   // = channel c
    const int wave  = __builtin_amdgcn_readfirstlane((int)(threadIdx.x >> 6)); // 0..7
    const int bh    = blockIdx.x;         // 0..223
    const int b     = bh / Hn;
    const int h     = bh - b * Hn;
    const int w0    = blockIdx.y * PIX;   // 0 or 28
    const int obase = blockIdx.z * 32 + wave * OG;   // this wave's o range

    // Stage x[b, :, h-1..h+1, w0-1..w0+28] into slab; pads (rows and cols)
    // staged as exact 0.0f. Once per block.
    const float* xb = x + b * (Cn * Hn * Wn);
    for (int i = threadIdx.x; i < 3 * Cn * SLABW; i += 512) {
        const int ws  = i % SLABW;
        const int t   = i / SLABW;
        const int c   = t & (Cn - 1);
        const int r   = t >> 6;
        const int row = h + r - 1;
        const int w   = w0 - 1 + ws;
        float v = 0.0f;
        if (row >= 0 && row < Hn && (unsigned)w < (unsigned)Wn)
            v = xb[(c * Hn + row) * Wn + w];
        slab[r][c][ws] = v;
    }

    // This wave's weights, lane = c: W[o,kw,kh,c] = wt[((o*3+kw)*3+kh)*64+c].
    // 36 coalesced 256B loads, once; lives in 36 VGPRs for the whole kernel.
    float wreg[OG][3][3];
    #pragma unroll
    for (int oo = 0; oo < OG; ++oo)
        #pragma unroll
        for (int kw = 0; kw < 3; ++kw)
            #pragma unroll
            for (int kh = 0; kh < 3; ++kh)
                wreg[oo][kh][kw] = wt[(((obase + oo) * 3 + kw) * 3 + kh) * Cn + lane];

    __syncthreads();

    int vcnt[OG];                         // lane p holds neg-count for pixel p
    #pragma unroll
    for (int oo = 0; oo < OG; ++oo) vcnt[oo] = 0;

    // Sliding 3-tap windows, one per kh row.
    float xl[3], xm[3];
    #pragma unroll
    for (int r = 0; r < 3; ++r) {
        xl[r] = slab[r][lane][0];
        xm[r] = slab[r][lane][1];
    }

#define PBODY(P)                                                              \
    do {                                                                      \
        float xr[3];                                                          \
        _Pragma("unroll")                                                     \
        for (int r = 0; r < 3; ++r) xr[r] = slab[r][lane][(P) + 2];           \
        _Pragma("unroll")                                                     \
        for (int oo = 0; oo < OG; ++oo) {                                     \
            int cnt = 0;                                                      \
            _Pragma("unroll")                                                 \
            for (int r = 0; r < 3; ++r) {                                     \
                const float s = (xl[r] * wreg[oo][r][0] +                     \
                                 xm[r] * wreg[oo][r][1])                      \
                              + xr[r] * wreg[oo][r][2];                       \
                cnt += (int)__popcll(__ballot(s < 0.0f));                     \
            }                                                                 \
            const int cs = __builtin_amdgcn_readfirstlane(cnt);              \
            WRITELANE(vcnt[oo], cs, P);                                       \
        }                                                                     \
        _Pragma("unroll")                                                     \
        for (int r = 0; r < 3; ++r) { xl[r] = xm[r]; xm[r] = xr[r]; }         \
    } while (0)

    PBODY(0);  PBODY(1);  PBODY(2);  PBODY(3);  PBODY(4);  PBODY(5);
    PBODY(6);  PBODY(7);  PBODY(8);  PBODY(9);  PBODY(10); PBODY(11);
    PBODY(12); PBODY(13); PBODY(14); PBODY(15); PBODY(16); PBODY(17);
    PBODY(18); PBODY(19); PBODY(20); PBODY(21); PBODY(22); PBODY(23);
    PBODY(24); PBODY(25); PBODY(26); PBODY(27);

    // out = nvalid*64 - 2*negcount (padded rows excluded; their staged-zero
    // sums are +-0 -> (s<0) false -> never counted).
    const int nvalid = 3 - (h == 0) - (h == Hn - 1);
    const float base = (float)(nvalid * Cn);
    if (lane < PIX) {
        float* ob = out + ((b * On + obase) * Hn + h) * Wn + w0 + lane;
        #pragma unroll
        for (int oo = 0; oo < OG; ++oo)
            ob[oo * Hn * Wn] = base - 2.0f * (float)vcnt[oo];
    }
}

extern "C" void kernel_launch(void* const* d_in, const int* in_sizes, int n_in,
                              void* d_out, int out_size, void* d_ws, size_t ws_size,
                              hipStream_t stream) {
    const float* x  = (const float*)d_in[0];
    const float* wt = (const float*)d_in[1];
    float* o        = (float*)d_out;
    dim3 grid(224, 2, 2);   // (b,h) x w-half x o-half; 8 waves x (28px, 4o)
    maj3_kernel<<<grid, dim3(512), 0, stream>>>(x, wt, o);
}